// Round 7
// baseline (587.905 us; speedup 1.0000x reference)
//
#include <hip/hip_runtime.h>
#include <cstddef>
#include <cstdint>

#define BB 4
#define SS 2048
#define EE 1024
#define HH 16
#define DD 64
#define FF 4096

typedef unsigned short u16;
typedef __attribute__((ext_vector_type(8))) short short8;   // 8 bf16 = 4 VGPR (MFMA A/B frag)
typedef __attribute__((ext_vector_type(4))) short short4v;
typedef __attribute__((ext_vector_type(16))) float f32x16;  // 32x32 MFMA C/D frag
typedef __attribute__((ext_vector_type(4))) unsigned u32x4;

__device__ __forceinline__ u16 f2bf(float x) {
    unsigned u = __builtin_bit_cast(unsigned, x);
    u += 0x7fffu + ((u >> 16) & 1u);   // round-to-nearest-even
    return (u16)(u >> 16);
}
__device__ __forceinline__ float bf2f(u16 h) {
    unsigned u = ((unsigned)h) << 16;
    return __builtin_bit_cast(float, u);
}
// raw 2^x (Q is pre-scaled by log2e at projection time, so exp(score)=exp2(score'))
__device__ __forceinline__ float ex2(float x) {
    float r;
    asm("v_exp_f32 %0, %1" : "=v"(r) : "v"(x));
    return r;
}
// pack 2 f32 -> 2 bf16 in one u32 (RNE), low half = lo
__device__ __forceinline__ unsigned cvtpk(float lo, float hi) {
    unsigned r;
    asm("v_cvt_pk_bf16_f32 %0, %1, %2" : "=v"(r) : "v"(lo), "v"(hi));
    return r;
}
// half-wave transpose x2: (a,b),(c,d) swapped; interleaved so the two
// independent permlanes cover each other's VALU hazard; s_nops guard the edges.
__device__ __forceinline__ void pl32swap2(unsigned &a, unsigned &b,
                                          unsigned &c, unsigned &d) {
    asm("s_nop 1\n\t"
        "v_permlane32_swap_b32 %0, %1\n\t"
        "v_permlane32_swap_b32 %2, %3\n\t"
        "s_nop 1"
        : "+v"(a), "+v"(b), "+v"(c), "+v"(d));
}
// XOR-swizzled byte offset into a [rows][128B] LDS tile
__device__ __forceinline__ int sw(int row, int lbyte) {
    return row * 128 + (lbyte ^ ((row & 7) << 4));
}

// async global->LDS DMA, 16B per lane; LDS dest is wave-uniform base + lane*16B
#define GLD_LDS16(g, l)                                                     \
    __builtin_amdgcn_global_load_lds(                                       \
        (const __attribute__((address_space(1))) void*)(g),                 \
        (__attribute__((address_space(3))) void*)(l), 16, 0, 0)

// ---------------------------------------------------------------------------
// fp32 -> bf16 elementwise convert (4 elems/thread)
// ---------------------------------------------------------------------------
__global__ __launch_bounds__(256) void cvt_bf(const float* __restrict__ in,
                                              u16* __restrict__ out, int n4) {
    const int i = blockIdx.x * 256 + threadIdx.x;
    if (i < n4) {
        float4 v = reinterpret_cast<const float4*>(in)[i];
        short4v o;
        o.x = (short)f2bf(v.x); o.y = (short)f2bf(v.y);
        o.z = (short)f2bf(v.z); o.w = (short)f2bf(v.w);
        reinterpret_cast<short4v*>(out)[i] = o;
    }
}

// ---------------------------------------------------------------------------
// Transpose + convert: out[c][r] = (bf16) in[r][c].  in: [R][C] fp32, batched.
// grid (R/64, C/64, batch)
// ---------------------------------------------------------------------------
__global__ __launch_bounds__(256) void transp_bf(const float* __restrict__ in,
                                                 u16* __restrict__ out, int R, int C) {
    __shared__ float T[64][65];
    const int r0 = blockIdx.x * 64, c0 = blockIdx.y * 64;
    const size_t zoff = (size_t)blockIdx.z * R * C;
    in += zoff; out += zoff;
    const int tid = threadIdx.x;
#pragma unroll 4
    for (int i = 0; i < 16; ++i) {
        int l = tid + i * 256;
        T[l >> 6][l & 63] = in[(size_t)(r0 + (l >> 6)) * C + c0 + (l & 63)];
    }
    __syncthreads();
#pragma unroll 4
    for (int i = 0; i < 16; ++i) {
        int l = tid + i * 256;
        out[(size_t)(c0 + (l >> 6)) * R + r0 + (l & 63)] = f2bf(T[l & 63][l >> 6]);
    }
}

// ---------------------------------------------------------------------------
// Pipelined bf16 GEMM: BM=256, BN=128, BK=64, 512 thr = 8 waves (4M x 2N),
// 32x32x16 MFMA, per-wave 64x64 output (acc 2x2 f32x16).
// PHASE-SPLIT schedule (T3+T4): 3 LDS buffers (144 KB); K-tile split into
// 4 phases (one K=16 quarter each): {4 ds_read || issue 1-2 gld_lds of tile
// t+2 -> barrier -> setprio -> 4 MFMA -> setprio -> barrier}; counted
// s_waitcnt vmcnt(6) once per tile (phase 3, before closing barrier) -- never
// drained in steady state.  Staging runs 2 tiles ahead; the 3rd buffer makes
// in-tile stage issue race-free (writes target buf (t+2)%3, whose last reader
// was tile t-1, barrier-separated).  sched_barrier(0) pins phase boundaries.
// XOR slot-swizzle via pre-swizzled global src (T2); XCD swizzle (T1).
// A [M][K] bf16 row-major (k inner); BT [N][K] bf16 (k inner). C row-major ldc=N.
// EPI: 0 = bf16 out * oscale | 1 = f32 out + f32 resid | 2 = bf16 out + bias + relu
//      3 = f32 out + bias + bf16 resid
//      4 = dual bf16 out: block cols [0,1024) -> Cout * oscale, cols
//          [1024,2048) -> Cout2 (Q|K fused projection, ldc 1024 each)
// ---------------------------------------------------------------------------
#define WAITV6 asm volatile("s_waitcnt vmcnt(6)" ::: "memory")

#define STAGE(p, k0u)                                                         \
    do {                                                                      \
        _Pragma("unroll")                                                     \
        for (int i_ = 0; i_ < 4; ++i_)                                        \
            GLD_LDS16(Ag + (size_t)(i_ * 64) * K + (k0u),                     \
                      &lds[(p) * 24576 + (i_ * 64 + w * 8) * 64]);            \
        _Pragma("unroll")                                                     \
        for (int j_ = 0; j_ < 2; ++j_)                                        \
            GLD_LDS16(Bg + (size_t)(j_ * 64) * K + (k0u),                     \
                      &lds[(p) * 24576 + 16384 + (j_ * 64 + w * 8) * 64]);    \
    } while (0)

template <int EPI>
__global__ __launch_bounds__(512, 2) void gemm256(const u16* __restrict__ A,
                                                  const u16* __restrict__ BT,
                                                  int K, int N, int gy,
                                                  void* __restrict__ Cout,
                                                  const float* __restrict__ bias,
                                                  const void* __restrict__ resid,
                                                  float oscale,
                                                  void* __restrict__ Cout2) {
    __shared__ __align__(16) u16 lds[3 * 24576];   // 3 bufs x (A 256*64 | B 128*64)
    // bijective XCD-aware block swizzle (T1)
    const int nwg = gridDim.x;
    const int bid = blockIdx.x;
    const int qq = nwg >> 3, rr = nwg & 7;
    const int xcd = bid & 7, lin = bid >> 3;
    const int wgid = (xcd < rr ? xcd * (qq + 1) : rr * (qq + 1) + (xcd - rr) * qq) + lin;
    const int x = wgid / gy, y = wgid % gy;
    const int m0 = x * 256, n0 = y * 128;

    const int tid = threadIdx.x;
    const int w = tid >> 6, l = tid & 63;
    const int l32 = l & 31, hf = l >> 5;
    const int wm = w >> 1, wn = w & 1;

    // staging source: thread (w,l) covers LDS row (i*64 + w*8 + l/8), slot l&7.
    // LDS[row][slot] must hold global chunk (slot ^ (row&7)); row&7 == l>>3.
    const int swz = ((l & 7) ^ (l >> 3)) * 8;                 // pre-swizzled src chunk
    const u16* Ag = A + (size_t)(m0 + w * 8 + (l >> 3)) * K + swz;
    const u16* Bg = BT + (size_t)(n0 + w * 8 + (l >> 3)) * K + swz;

    const int NTt = K >> 6;
    f32x16 acc[2][2] = {};

    // prologue: tiles 0,1 -> bufs 0,1 (6 loads each)
    STAGE(0, 0);
    STAGE(1, 64);
    WAITV6;                                           // tile 0 landed (tile 1 in flight)
    __builtin_amdgcn_sched_barrier(0);
    __builtin_amdgcn_s_barrier();                     // tile 0 visible to all waves
    __builtin_amdgcn_sched_barrier(0);

    int bp = 0;                                       // buffer of tile t
    for (int t = 0; t < NTt; ++t) {
        const u16* Ab = &lds[bp * 24576];
        const u16* Bb = &lds[bp * 24576 + 16384];
        const int bs = (bp + 2 >= 3) ? bp - 1 : bp + 2;   // (bp+2)%3: tile t+2's buf
        const bool st = (t + 2) < NTt;
        const size_t k2 = (size_t)(t + 2) * 64;
        u16* sd = &lds[bs * 24576];
#pragma unroll
        for (int ks = 0; ks < 4; ++ks) {
            const int cs = (((ks * 2 + hf) ^ (l32 & 7)) * 8);   // swizzled slot read
            short8 af0 = *(const short8*)&Ab[(wm * 64 + l32) * 64 + cs];
            short8 af1 = *(const short8*)&Ab[(wm * 64 + 32 + l32) * 64 + cs];
            short8 bf0 = *(const short8*)&Bb[(wn * 64 + l32) * 64 + cs];
            short8 bf1 = *(const short8*)&Bb[(wn * 64 + 32 + l32) * 64 + cs];
            if (st) {   // spread tile t+2's 6 loads across phases: 2,2,1,1
                if (ks == 0) {
                    GLD_LDS16(Ag + k2, sd + (w * 8) * 64);
                    GLD_LDS16(Ag + (size_t)64 * K + k2, sd + (64 + w * 8) * 64);
                } else if (ks == 1) {
                    GLD_LDS16(Ag + (size_t)128 * K + k2, sd + (128 + w * 8) * 64);
                    GLD_LDS16(Ag + (size_t)192 * K + k2, sd + (192 + w * 8) * 64);
                } else if (ks == 2) {
                    GLD_LDS16(Bg + k2, sd + 16384 + (w * 8) * 64);
                } else {
                    GLD_LDS16(Bg + (size_t)64 * K + k2, sd + 16384 + (64 + w * 8) * 64);
                }
            }
            __builtin_amdgcn_sched_barrier(0);
            __builtin_amdgcn_s_barrier();             // all waves: reads issued
            __builtin_amdgcn_sched_barrier(0);
            __builtin_amdgcn_s_setprio(1);
            acc[0][0] = __builtin_amdgcn_mfma_f32_32x32x16_bf16(af0, bf0, acc[0][0], 0, 0, 0);
            acc[0][1] = __builtin_amdgcn_mfma_f32_32x32x16_bf16(af0, bf1, acc[0][1], 0, 0, 0);
            acc[1][0] = __builtin_amdgcn_mfma_f32_32x32x16_bf16(af1, bf0, acc[1][0], 0, 0, 0);
            acc[1][1] = __builtin_amdgcn_mfma_f32_32x32x16_bf16(af1, bf1, acc[1][1], 0, 0, 0);
            __builtin_amdgcn_s_setprio(0);
            __builtin_amdgcn_sched_barrier(0);
            if (ks == 3) {
                WAITV6;                               // tile t+1 landed (t+2's 6 in flight)
                __builtin_amdgcn_sched_barrier(0);
            }
            __builtin_amdgcn_s_barrier();             // end of phase
            __builtin_amdgcn_sched_barrier(0);
        }
        bp = (bp + 1 >= 3) ? 0 : bp + 1;
    }

    // EPI==4: per-block output select (block is entirely Q-side or K-side)
    u16* dst4 = nullptr;
    float sc4 = 1.0f;
    if (EPI == 4) {
        const bool isK = (n0 >= 1024);
        dst4 = isK ? (u16*)Cout2 : (u16*)Cout;
        sc4 = isK ? 1.0f : oscale;
    }

#pragma unroll
    for (int mb = 0; mb < 2; ++mb)
#pragma unroll
        for (int nb = 0; nb < 2; ++nb) {
            const int col = n0 + wn * 64 + nb * 32 + l32;
#pragma unroll
            for (int r = 0; r < 16; ++r) {
                const int row = m0 + wm * 64 + mb * 32 + (r & 3) + 8 * (r >> 2) + 4 * hf;
                float v = acc[mb][nb][r];
                const size_t idx = (size_t)row * N + col;
                if (EPI == 0) {
                    ((u16*)Cout)[idx] = f2bf(v * oscale);
                } else if (EPI == 1) {
                    ((float*)Cout)[idx] = v + ((const float*)resid)[idx];
                } else if (EPI == 2) {
                    v += bias[col];
                    ((u16*)Cout)[idx] = f2bf(fmaxf(v, 0.f));
                } else if (EPI == 3) {
                    v += bias[col] + bf2f(((const u16*)resid)[idx]);
                    ((float*)Cout)[idx] = v;
                } else {
                    dst4[(size_t)row * 1024 + (col & 1023)] = f2bf(v * sc4);
                }
            }
        }
}

// ---------------------------------------------------------------------------
// Attention pass 1 (32x32 MFMA) + fused V-scale.
// l_t = sum_s exp2(score'); then Vt[h*64+d][b*SS+t] *= 0.125/l_t in the tail.
// K B-frags in regs (loop-invariant, col t); Q staged in double-buffered
// XOR-swizzled LDS, ONE barrier/iter; single-v_exp (Q pre-scaled by log2e).
// 1-D grid 1024, XCD swizzle groups all 16 t-tiles of a (b,h) on one XCD.
// ---------------------------------------------------------------------------
__global__ __launch_bounds__(256) void stats32(const u16* __restrict__ Qg,
                                               const u16* __restrict__ Kg,
                                               u16* __restrict__ Vtg) {
    __shared__ u16 Qs[2][64 * 64];   // [dbuf][s][d], swizzled 128B rows
    __shared__ float lbuf[128];
    const int bid = blockIdx.x;                     // nwg = 1024 (div by 8)
    const int wgid = (bid & 7) * 128 + (bid >> 3);  // contiguous runs per XCD
    const int t0 = (wgid & 15) * 128;
    const int bh = wgid >> 4;
    const int b = bh >> 4, h = bh & 15;
    const int tid = threadIdx.x;
    const int w = tid >> 6, l = tid & 63;
    const int l32 = l & 31, hf = l >> 5;
    const u16* Qp = Qg + (size_t)b * SS * 1024 + h * 64;
    const u16* Kp = Kg + (size_t)b * SS * 1024 + h * 64;
    const int sr = tid >> 3, dg = (tid & 7) * 8;    // staging row / u16 chunk

    // K B-frags: col t = t0 + w*32 + l32, k(d) = ks*16 + hf*8 + j
    short8 kf[4];
#pragma unroll
    for (int ks = 0; ks < 4; ++ks)
        kf[ks] = *(const short8*)(Kp + (size_t)(t0 + w * 32 + l32) * 1024 + ks * 16 + hf * 8);

    // prologue: tile 0 -> buf0, tile 1 -> regs
    short8 pq0 = *(const short8*)(Qp + (size_t)sr * 1024 + dg);
    short8 pq1 = *(const short8*)(Qp + (size_t)(sr + 32) * 1024 + dg);
    *(short8*)((char*)Qs[0] + sw(sr, dg * 2)) = pq0;
    *(short8*)((char*)Qs[0] + sw(sr + 32, dg * 2)) = pq1;
    pq0 = *(const short8*)(Qp + (size_t)(64 + sr) * 1024 + dg);
    pq1 = *(const short8*)(Qp + (size_t)(64 + sr + 32) * 1024 + dg);
    __syncthreads();

    float ls0 = 0.f, ls1 = 0.f;
    for (int st = 0; st < 32; ++st) {
        const int p = st & 1;
        if (st + 1 < 32) {   // stage tile st+1 (regs loaded last iter / prologue)
            *(short8*)((char*)Qs[p ^ 1] + sw(sr, dg * 2)) = pq0;
            *(short8*)((char*)Qs[p ^ 1] + sw(sr + 32, dg * 2)) = pq1;
        }
        if (st + 2 < 32) {   // issue tile st+2 global loads (hidden under MFMA)
            const int s1 = (st + 2) * 64;
            pq0 = *(const short8*)(Qp + (size_t)(s1 + sr) * 1024 + dg);
            pq1 = *(const short8*)(Qp + (size_t)(s1 + sr + 32) * 1024 + dg);
        }
        f32x16 sc0 = {}, sc1 = {};
        __builtin_amdgcn_s_setprio(1);
#pragma unroll
        for (int ks = 0; ks < 4; ++ks) {
            short8 a0 = *(const short8*)((char*)Qs[p] + sw(l32, ks * 32 + hf * 16));
            short8 a1 = *(const short8*)((char*)Qs[p] + sw(32 + l32, ks * 32 + hf * 16));
            sc0 = __builtin_amdgcn_mfma_f32_32x32x16_bf16(a0, kf[ks], sc0, 0, 0, 0);
            sc1 = __builtin_amdgcn_mfma_f32_32x32x16_bf16(a1, kf[ks], sc1, 0, 0, 0);
        }
        __builtin_amdgcn_s_setprio(0);
#pragma unroll
        for (int r = 0; r < 16; ++r) { ls0 += ex2(sc0[r]); ls1 += ex2(sc1[r]); }
        __syncthreads();   // release buf p, publish buf p^1
    }
    float lsum = ls0 + ls1;
    lsum += __shfl_xor(lsum, 32);          // combine hf halves (same t)
    if (hf == 0) lbuf[w * 32 + l32] = 0.125f / lsum;
    __syncthreads();

    // fused vscale: 64 rows (d) x 128 cols (t); thread = (d = tid>>2, 32 cols)
    const int d = tid >> 2, cb = (tid & 3) * 32;
    u16* vp = Vtg + (size_t)(h * 64 + d) * 8192 + b * SS + t0 + cb;
#pragma unroll
    for (int j = 0; j < 4; ++j) {
        short8 v = *(short8*)(vp + j * 8);
        short8 o;
#pragma unroll
        for (int i = 0; i < 8; ++i)
            o[i] = (short)f2bf(bf2f((u16)v[i]) * lbuf[cb + j * 8 + i]);
        *(short8*)(vp + j * 8) = o;
    }
}

// ---------------------------------------------------------------------------
// Attention pass 2 (fused), 32x32x16 MFMA with in-register P.
// Each wave owns TWO s-blocks (A: s0+w*32, B: s0+128+w*32); every K/V LDS
// fragment read feeds 2 MFMAs -> LDS reads per MFMA halved (cross-wave
// redundancy amortized in-register).  Iteration processes t-halves (th=0:
// t 0..31, th=1: t 32..63) sequentially so only one sc pair is live.
// Double-buffered K/V LDS tiles, ONE barrier per iter.  P = bf16(exp2(S))
// via cvt_pk + permlane32_swap (R3-proven copy + pl32swap2 pattern).
// 1-D grid 512 with XCD swizzle (8 bh per XCD; K/V L2-resident).
// ---------------------------------------------------------------------------
__global__ __launch_bounds__(256) void pv_fused(const u16* __restrict__ Qg,
                                                const u16* __restrict__ Kg,
                                                const u16* __restrict__ Vtg,
                                                u16* __restrict__ vecbf) {
    __shared__ u16 Ks[2][64 * 64];   // [dbuf][t][d], swizzled 128B rows
    __shared__ u16 Vs[2][64 * 64];   // [dbuf][d][t], swizzled 128B rows
    const int bid = blockIdx.x;                    // nwg = 512
    const int wgid = (bid & 7) * 64 + (bid >> 3);  // 64 consecutive per XCD
    const int s0 = (wgid & 7) * 256;
    const int bh = wgid >> 3;
    const int b = bh >> 4, h = bh & 15;
    const int tid = threadIdx.x;
    const int w = tid >> 6, l = tid & 63;
    const int l32 = l & 31, hf = l >> 5;
    const u16* Qp = Qg + (size_t)b * SS * 1024 + h * 64;
    const u16* Kp = Kg + (size_t)b * SS * 1024 + h * 64;
    const u16* Vp = Vtg + (size_t)h * 64 * 8192 + (size_t)b * SS;
    const int sr = tid >> 3, dg = (tid & 7) * 8;   // staging row / u16 chunk

    // Q B-frags (loop-invariant), two s-blocks per wave:
    //   A: col s = s0 + w*32 + l32;  B: col s = s0 + 128 + w*32 + l32
    short8 qfA[4], qfB[4];
#pragma unroll
    for (int ks = 0; ks < 4; ++ks) {
        qfA[ks] = *(const short8*)(Qp + (size_t)(s0 + w * 32 + l32) * 1024 + ks * 16 + hf * 8);
        qfB[ks] = *(const short8*)(Qp + (size_t)(s0 + 128 + w * 32 + l32) * 1024 + ks * 16 + hf * 8);
    }

    // prologue: tile 0 -> buf0, tile 1 -> regs
    short8 pk0 = *(const short8*)(Kp + (size_t)sr * 1024 + dg);
    short8 pk1 = *(const short8*)(Kp + (size_t)(sr + 32) * 1024 + dg);
    short8 pv0 = *(const short8*)(Vp + (size_t)sr * 8192 + dg);
    short8 pv1 = *(const short8*)(Vp + (size_t)(sr + 32) * 8192 + dg);
    *(short8*)((char*)Ks[0] + sw(sr, dg * 2)) = pk0;
    *(short8*)((char*)Ks[0] + sw(sr + 32, dg * 2)) = pk1;
    *(short8*)((char*)Vs[0] + sw(sr, dg * 2)) = pv0;
    *(short8*)((char*)Vs[0] + sw(sr + 32, dg * 2)) = pv1;
    pk0 = *(const short8*)(Kp + (size_t)(64 + sr) * 1024 + dg);
    pk1 = *(const short8*)(Kp + (size_t)(64 + sr + 32) * 1024 + dg);
    pv0 = *(const short8*)(Vp + (size_t)sr * 8192 + 64 + dg);
    pv1 = *(const short8*)(Vp + (size_t)(sr + 32) * 8192 + 64 + dg);
    __syncthreads();

    f32x16 accA[2] = {}, accB[2] = {};   // O[s][d] for the two s-blocks
    for (int tt = 0; tt < 32; ++tt) {
        const int p = tt & 1;
        if (tt + 1 < 32) {   // stage tile tt+1
            *(short8*)((char*)Ks[p ^ 1] + sw(sr, dg * 2)) = pk0;
            *(short8*)((char*)Ks[p ^ 1] + sw(sr + 32, dg * 2)) = pk1;
            *(short8*)((char*)Vs[p ^ 1] + sw(sr, dg * 2)) = pv0;
            *(short8*)((char*)Vs[p ^ 1] + sw(sr + 32, dg * 2)) = pv1;
        }
        if (tt + 2 < 32) {   // issue tile tt+2 loads
            const int t1 = (tt + 2) * 64;
            pk0 = *(const short8*)(Kp + (size_t)(t1 + sr) * 1024 + dg);
            pk1 = *(const short8*)(Kp + (size_t)(t1 + sr + 32) * 1024 + dg);
            pv0 = *(const short8*)(Vp + (size_t)sr * 8192 + t1 + dg);
            pv1 = *(const short8*)(Vp + (size_t)(sr + 32) * 8192 + t1 + dg);
        }
        // t-halves: th covers tile rows t in [th*32, th*32+32)
#pragma unroll
        for (int th = 0; th < 2; ++th) {
            // S^T[t][s]: A-operand = K rows (th*32 + l32), one read feeds both
            // s-blocks.  C: col=s=l32, row t = th*32 + (reg&3)+8*(reg>>2)+4*hf
            f32x16 scA = {}, scB = {};
            __builtin_amdgcn_s_setprio(1);
#pragma unroll
            for (int ks = 0; ks < 4; ++ks) {
                short8 a0 = *(const short8*)((char*)Ks[p] + sw(th * 32 + l32, ks * 32 + hf * 16));
                scA = __builtin_amdgcn_mfma_f32_32x32x16_bf16(a0, qfA[ks], scA, 0, 0, 0);
                scB = __builtin_amdgcn_mfma_f32_32x32x16_bf16(a0, qfB[ks], scB, 0, 0, 0);
            }
            __builtin_amdgcn_s_setprio(0);
            // P = exp2(S) -> packed bf16 pairs (t, t+1) per u32
            unsigned cpA[8], cpB[8];
#pragma unroll
            for (int p2 = 0; p2 < 8; ++p2) {
                cpA[p2] = cvtpk(ex2(scA[2 * p2]), ex2(scA[2 * p2 + 1]));
                cpB[p2] = cvtpk(ex2(scB[2 * p2]), ex2(scB[2 * p2 + 1]));
            }
            // A-frags for PV: ks2 = th*2 + q covers t = 16*ks2 + 8*hf + j
            short8 paA[2], paB[2];
#pragma unroll
            for (int q = 0; q < 2; ++q) {
                const int c = q * 4;
                unsigned a0w = cpA[c + 0], a2w = cpA[c + 2];
                unsigned a1w = cpA[c + 1], a3w = cpA[c + 3];
                pl32swap2(a0w, a2w, a1w, a3w);
                u32x4 tA; tA.x = a0w; tA.y = a1w; tA.z = a2w; tA.w = a3w;
                paA[q] = __builtin_bit_cast(short8, tA);
                unsigned b0w = cpB[c + 0], b2w = cpB[c + 2];
                unsigned b1w = cpB[c + 1], b3w = cpB[c + 3];
                pl32swap2(b0w, b2w, b1w, b3w);
                u32x4 tB; tB.x = b0w; tB.y = b1w; tB.z = b2w; tB.w = b3w;
                paB[q] = __builtin_bit_cast(short8, tB);
            }
            // O += P @ Vtilde: each V frag read feeds both s-blocks
            __builtin_amdgcn_s_setprio(1);
#pragma unroll
            for (int q = 0; q < 2; ++q) {
                const int ks2 = th * 2 + q;
#pragma unroll
                for (int nf = 0; nf < 2; ++nf) {
                    short8 bfr = *(const short8*)((char*)Vs[p] + sw(nf * 32 + l32, ks2 * 32 + hf * 16));
                    accA[nf] = __builtin_amdgcn_mfma_f32_32x32x16_bf16(paA[q], bfr, accA[nf], 0, 0, 0);
                    accB[nf] = __builtin_amdgcn_mfma_f32_32x32x16_bf16(paB[q], bfr, accB[nf], 0, 0, 0);
                }
            }
            __builtin_amdgcn_s_setprio(0);
        }
        __syncthreads();   // release buf p, publish buf p^1
    }
#pragma unroll
    for (int nf = 0; nf < 2; ++nf) {
        const int col = h * 64 + nf * 32 + l32;
#pragma unroll
        for (int r = 0; r < 16; ++r) {
            const int ro = (r & 3) + 8 * (r >> 2) + 4 * hf;
            const int srowA = s0 + w * 32 + ro;
            vecbf[(size_t)(b * SS + srowA) * 1024 + col] = f2bf(accA[nf][r]);
            const int srowB = s0 + 128 + w * 32 + ro;
            vecbf[(size_t)(b * SS + srowB) * 1024 + col] = f2bf(accB[nf][r]);
        }
    }
}

// ---------------------------------------------------------------------------
// LayerNorm over last dim (E=1024), fp32 in -> bf16 out
// ---------------------------------------------------------------------------
__global__ __launch_bounds__(256) void ln_bf_kernel(const float* __restrict__ buf,
                                                    const float* __restrict__ g,
                                                    const float* __restrict__ be,
                                                    u16* __restrict__ outbf) {
    const int row = blockIdx.x;
    const int tid = threadIdx.x;
    const float* p = buf + (size_t)row * EE;
    float4 x = reinterpret_cast<const float4*>(p)[tid];
    float s = x.x + x.y + x.z + x.w;
    __shared__ float red[4];
#pragma unroll
    for (int o = 32; o > 0; o >>= 1) s += __shfl_down(s, o);
    const int wid = tid >> 6, lane = tid & 63;
    if (lane == 0) red[wid] = s;
    __syncthreads();
    const float mu = (red[0] + red[1] + red[2] + red[3]) * (1.0f / EE);
    __syncthreads();
    const float dx = x.x - mu, dy = x.y - mu, dz = x.z - mu, dw = x.w - mu;
    float v = dx * dx + dy * dy + dz * dz + dw * dw;
#pragma unroll
    for (int o = 32; o > 0; o >>= 1) v += __shfl_down(v, o);
    if (lane == 0) red[wid] = v;
    __syncthreads();
    const float var = (red[0] + red[1] + red[2] + red[3]) * (1.0f / EE);
    const float rs = rsqrtf(var + 1e-5f);
    float4 gv = reinterpret_cast<const float4*>(g)[tid];
    float4 bv = reinterpret_cast<const float4*>(be)[tid];
    short4v o;
    o.x = (short)f2bf(dx * rs * gv.x + bv.x);
    o.y = (short)f2bf(dy * rs * gv.y + bv.y);
    o.z = (short)f2bf(dz * rs * gv.z + bv.z);
    o.w = (short)f2bf(dw * rs * gv.w + bv.w);
    reinterpret_cast<short4v*>(outbf + (size_t)row * EE)[tid] = o;
}

// In-place fp32 LayerNorm (final output)
__global__ __launch_bounds__(256) void ln_kernel(float* __restrict__ buf,
                                                 const float* __restrict__ g,
                                                 const float* __restrict__ be) {
    const int row = blockIdx.x;
    const int tid = threadIdx.x;
    float* p = buf + (size_t)row * EE;
    float4 x = reinterpret_cast<float4*>(p)[tid];
    float s = x.x + x.y + x.z + x.w;
    __shared__ float red[4];
#pragma unroll
    for (int o = 32; o > 0; o >>= 1) s += __shfl_down(s, o);
    const int wid = tid >> 6, lane = tid & 63;
    if (lane == 0) red[wid] = s;
    __syncthreads();
    const float mu = (red[0] + red[1] + red[2] + red[3]) * (1.0f / EE);
    __syncthreads();
    const float dx = x.x - mu, dy = x.y - mu, dz = x.z - mu, dw = x.w - mu;
    float v = dx * dx + dy * dy + dz * dz + dw * dw;
#pragma unroll
    for (int o = 32; o > 0; o >>= 1) v += __shfl_down(v, o);
    if (lane == 0) red[wid] = v;
    __syncthreads();
    const float var = (red[0] + red[1] + red[2] + red[3]) * (1.0f / EE);
    const float rs = rsqrtf(var + 1e-5f);
    float4 gv = reinterpret_cast<const float4*>(g)[tid];
    float4 bv = reinterpret_cast<const float4*>(be)[tid];
    float4 y;
    y.x = dx * rs * gv.x + bv.x;
    y.y = dy * rs * gv.y + bv.y;
    y.z = dz * rs * gv.z + bv.z;
    y.w = dw * rs * gv.w + bv.w;
    reinterpret_cast<float4*>(p)[tid] = y;
}

// ---------------------------------------------------------------------------
extern "C" void kernel_launch(void* const* d_in, const int* in_sizes, int n_in,
                              void* d_out, int out_size, void* d_ws, size_t ws_size,
                              hipStream_t stream) {
    const float* X     = (const float*)d_in[0];
    const float* WQ    = (const float*)d_in[1];
    const float* WK    = (const float*)d_in[2];
    const float* WV    = (const float*)d_in[3];
    const float* WO    = (const float*)d_in[4];
    const float* gamma = (const float*)d_in[5];
    const float* beta  = (const float*)d_in[6];
    const float* W1    = (const float*)d_in[7];
    const float* b1    = (const float*)d_in[8];
    const float* W2    = (const float*)d_in[9];
    const float* b2    = (const float*)d_in[10];
    float* out = (float*)d_out;

    char* ws = (char*)d_ws;
    const size_t MB = 1024 * 1024;
    u16* WQT   = (u16*)(ws + 0);          // 2 MB [H][D][E]   (WQT|WKT contiguous
    u16* WKT   = (u16*)(ws + 2 * MB);     //  -> fused [2048][1024] B for QK proj)
    u16* WVT   = (u16*)(ws + 4 * MB);
    u16* WOT   = (u16*)(ws + 6 * MB);     // 2 MB [E][H*D]
    u16* W1T   = (u16*)(ws + 8 * MB);     // 8 MB [F][E]
    u16* W2T   = (u16*)(ws + 16 * MB);    // 8 MB [E][F]
    u16* Qbf   = (u16*)(ws + 25 * MB);    // 16 MB [B*S][H*D] (pre-scaled by log2e)
    u16* Kbf   = (u16*)(ws + 41 * MB);    // 16 MB
    u16* Vt    = (u16*)(ws + 57 * MB);    // 16 MB [H*D][B*S]
    u16* vecbf = (u16*)(ws + 73 * MB);    // 16 MB att_vec bf16
    u16* hid   = (u16*)(ws + 25 * MB);    // 64 MB FFN hidden, overlays Q/K/Vt/vec
    u16* Xbf   = (u16*)(ws + 89 * MB);    // 16 MB
    float* vatt  = (float*)(ws + 105 * MB); // 32 MB fp32 (pre-LN1)
    u16*   ln1bf = (u16*)(ws + 137 * MB);   // 16 MB LN1 out

    const int NT = BB * SS;   // 8192 tokens

    // --- one-time converts / weight transposes (bf16, k-innermost) ---
    cvt_bf<<<8192, 256, 0, stream>>>(X, Xbf, NT * EE / 4);
    transp_bf<<<dim3(16, 1, 16), 256, 0, stream>>>(WQ, WQT, EE, DD);
    transp_bf<<<dim3(16, 1, 16), 256, 0, stream>>>(WK, WKT, EE, DD);
    transp_bf<<<dim3(16, 1, 16), 256, 0, stream>>>(WV, WVT, EE, DD);
    transp_bf<<<dim3(16, 16, 1), 256, 0, stream>>>(WO, WOT, HH * DD, EE);
    transp_bf<<<dim3(16, 64, 1), 256, 0, stream>>>(W1, W1T, EE, FF);
    transp_bf<<<dim3(64, 16, 1), 256, 0, stream>>>(W2, W2T, FF, EE);

    // --- projections: Q+K fused (B = [WQT;WKT] contiguous, 512 blocks);
    //     Q scaled by log2e so attention exp == single v_exp_f32 ---
    gemm256<4><<<512, 512, 0, stream>>>(Xbf, WQT, 1024, 2048, 16, Qbf, nullptr, nullptr, 1.44269504089f, Kbf);
    gemm256<0><<<256, 512, 0, stream>>>(WVT, Xbf, 1024, 8192, 64, Vt, nullptr, nullptr, 1.0f, nullptr);

    // --- attention (column softmax then /8), fused path ---
    stats32<<<1024, 256, 0, stream>>>(Qbf, Kbf, Vt);          // l stats + V scale
    pv_fused<<<512, 256, 0, stream>>>(Qbf, Kbf, Vt, vecbf);

    // --- WO + residual X -> vatt (fp32), LN1 -> ln1bf ---
    gemm256<1><<<256, 512, 0, stream>>>(vecbf, WOT, 1024, 1024, 8, vatt, nullptr, X, 1.0f, nullptr);
    ln_bf_kernel<<<NT, 256, 0, stream>>>(vatt, gamma, beta, ln1bf);

    // --- FFN ---
    gemm256<2><<<1024, 512, 0, stream>>>(ln1bf, W1T, 1024, FF, 32, hid, b1, nullptr, 1.0f, nullptr);
    gemm256<3><<<256, 512, 0, stream>>>(hid, W2T, FF, 1024, 8, out, b2, ln1bf, 1.0f, nullptr);

    // --- final LN in place on d_out ---
    ln_kernel<<<NT, 256, 0, stream>>>(out, gamma, beta);
}

// Round 8
// 542.695 us; speedup vs baseline: 1.0833x; 1.0833x over previous
//
#include <hip/hip_runtime.h>
#include <cstddef>
#include <cstdint>

#define BB 4
#define SS 2048
#define EE 1024
#define HH 16
#define DD 64
#define FF 4096

typedef unsigned short u16;
typedef __attribute__((ext_vector_type(8))) short short8;   // 8 bf16 = 4 VGPR (MFMA A/B frag)
typedef __attribute__((ext_vector_type(4))) short short4v;
typedef __attribute__((ext_vector_type(16))) float f32x16;  // 32x32 MFMA C/D frag
typedef __attribute__((ext_vector_type(4))) unsigned u32x4;

__device__ __forceinline__ u16 f2bf(float x) {
    unsigned u = __builtin_bit_cast(unsigned, x);
    u += 0x7fffu + ((u >> 16) & 1u);   // round-to-nearest-even
    return (u16)(u >> 16);
}
__device__ __forceinline__ float bf2f(u16 h) {
    unsigned u = ((unsigned)h) << 16;
    return __builtin_bit_cast(float, u);
}
// raw 2^x (Q is pre-scaled by log2e at projection time, so exp(score)=exp2(score'))
__device__ __forceinline__ float ex2(float x) {
    float r;
    asm("v_exp_f32 %0, %1" : "=v"(r) : "v"(x));
    return r;
}
// pack 2 f32 -> 2 bf16 in one u32 (RNE), low half = lo
__device__ __forceinline__ unsigned cvtpk(float lo, float hi) {
    unsigned r;
    asm("v_cvt_pk_bf16_f32 %0, %1, %2" : "=v"(r) : "v"(lo), "v"(hi));
    return r;
}
// half-wave transpose x2: (a,b),(c,d) swapped; interleaved so the two
// independent permlanes cover each other's VALU hazard; s_nops guard the edges.
__device__ __forceinline__ void pl32swap2(unsigned &a, unsigned &b,
                                          unsigned &c, unsigned &d) {
    asm("s_nop 1\n\t"
        "v_permlane32_swap_b32 %0, %1\n\t"
        "v_permlane32_swap_b32 %2, %3\n\t"
        "s_nop 1"
        : "+v"(a), "+v"(b), "+v"(c), "+v"(d));
}
// XOR-swizzled byte offset into a [rows][128B] LDS tile
__device__ __forceinline__ int sw(int row, int lbyte) {
    return row * 128 + (lbyte ^ ((row & 7) << 4));
}

// async global->LDS DMA, 16B per lane; LDS dest is wave-uniform base + lane*16B
#define GLD_LDS16(g, l)                                                     \
    __builtin_amdgcn_global_load_lds(                                       \
        (const __attribute__((address_space(1))) void*)(g),                 \
        (__attribute__((address_space(3))) void*)(l), 16, 0, 0)

// ---------------------------------------------------------------------------
// fp32 -> bf16 elementwise convert (4 elems/thread)
// ---------------------------------------------------------------------------
__global__ __launch_bounds__(256) void cvt_bf(const float* __restrict__ in,
                                              u16* __restrict__ out, int n4) {
    const int i = blockIdx.x * 256 + threadIdx.x;
    if (i < n4) {
        float4 v = reinterpret_cast<const float4*>(in)[i];
        short4v o;
        o.x = (short)f2bf(v.x); o.y = (short)f2bf(v.y);
        o.z = (short)f2bf(v.z); o.w = (short)f2bf(v.w);
        reinterpret_cast<short4v*>(out)[i] = o;
    }
}

// ---------------------------------------------------------------------------
// Transpose + convert: out[c][r] = (bf16) in[r][c].  in: [R][C] fp32, batched.
// grid (R/64, C/64, batch)
// ---------------------------------------------------------------------------
__global__ __launch_bounds__(256) void transp_bf(const float* __restrict__ in,
                                                 u16* __restrict__ out, int R, int C) {
    __shared__ float T[64][65];
    const int r0 = blockIdx.x * 64, c0 = blockIdx.y * 64;
    const size_t zoff = (size_t)blockIdx.z * R * C;
    in += zoff; out += zoff;
    const int tid = threadIdx.x;
#pragma unroll 4
    for (int i = 0; i < 16; ++i) {
        int l = tid + i * 256;
        T[l >> 6][l & 63] = in[(size_t)(r0 + (l >> 6)) * C + c0 + (l & 63)];
    }
    __syncthreads();
#pragma unroll 4
    for (int i = 0; i < 16; ++i) {
        int l = tid + i * 256;
        out[(size_t)(c0 + (l >> 6)) * R + r0 + (l & 63)] = f2bf(T[l & 63][l >> 6]);
    }
}

// ---------------------------------------------------------------------------
// Pipelined bf16 GEMM (R6-proven schedule): BM=256, BN=128, BK=64, 512 thr =
// 8 waves (4M x 2N), 32x32x16 MFMA, per-wave 64x64 output (acc 2x2 f32x16).
// Double-buffered 96KB LDS; counted s_waitcnt vmcnt(6) (T3+T4); raw s_barrier;
// setprio around MFMA (T5); XOR slot-swizzle via pre-swizzled global src (T2).
// A [M][K] bf16 row-major (k inner); BT [N][K] bf16 (k inner). C row-major ldc=N.
// EPI: 0 = bf16 out * oscale | 1 = f32 out + f32 resid | 2 = bf16 out + bias + relu
//      3 = f32 out + bias + bf16 resid
//      4 = dual bf16 out: block cols [0,1024) -> Cout * oscale, cols
//          [1024,2048) -> Cout2 (Q|K fused projection, ldc 1024 each)
// ---------------------------------------------------------------------------
#define WAITV6 asm volatile("s_waitcnt vmcnt(6)" ::: "memory")
#define WAITV0 asm volatile("s_waitcnt vmcnt(0)" ::: "memory")

#define STAGE(p, k0u)                                                         \
    do {                                                                      \
        _Pragma("unroll")                                                     \
        for (int i_ = 0; i_ < 4; ++i_)                                        \
            GLD_LDS16(Ag + (size_t)(i_ * 64) * K + (k0u),                     \
                      &lds[(p) * 24576 + (i_ * 64 + w * 8) * 64]);            \
        _Pragma("unroll")                                                     \
        for (int j_ = 0; j_ < 2; ++j_)                                        \
            GLD_LDS16(Bg + (size_t)(j_ * 64) * K + (k0u),                     \
                      &lds[(p) * 24576 + 16384 + (j_ * 64 + w * 8) * 64]);    \
    } while (0)

template <int EPI>
__global__ __launch_bounds__(512, 2) void gemm256(const u16* __restrict__ A,
                                                  const u16* __restrict__ BT,
                                                  int K, int N, int gy,
                                                  void* __restrict__ Cout,
                                                  const float* __restrict__ bias,
                                                  const void* __restrict__ resid,
                                                  float oscale,
                                                  void* __restrict__ Cout2) {
    __shared__ __align__(16) u16 lds[2 * 24576];   // [dbuf][A 256*64 | B 128*64]
    // bijective XCD-aware block swizzle (T1)
    const int nwg = gridDim.x;
    const int bid = blockIdx.x;
    const int qq = nwg >> 3, rr = nwg & 7;
    const int xcd = bid & 7, lin = bid >> 3;
    const int wgid = (xcd < rr ? xcd * (qq + 1) : rr * (qq + 1) + (xcd - rr) * qq) + lin;
    const int x = wgid / gy, y = wgid % gy;
    const int m0 = x * 256, n0 = y * 128;

    const int tid = threadIdx.x;
    const int w = tid >> 6, l = tid & 63;
    const int l32 = l & 31, hf = l >> 5;
    const int wm = w >> 1, wn = w & 1;

    // staging source: thread (w,l) covers LDS row (i*64 + w*8 + l/8), slot l&7.
    // LDS[row][slot] must hold global chunk (slot ^ (row&7)); row&7 == l>>3.
    const int swz = ((l & 7) ^ (l >> 3)) * 8;                 // pre-swizzled src chunk
    const u16* Ag = A + (size_t)(m0 + w * 8 + (l >> 3)) * K + swz;
    const u16* Bg = BT + (size_t)(n0 + w * 8 + (l >> 3)) * K + swz;

    const int NTt = K >> 6;
    f32x16 acc[2][2] = {};

    // prologue: tiles 0 and 1 in flight (6 per-wave loads each)
    STAGE(0, 0);
    STAGE(1, 64);

    for (int t = 0; t < NTt; ++t) {
        const int p = t & 1;
        if (t < NTt - 1) { WAITV6; } else { WAITV0; }   // tile t landed (t+1 stays in flight)
        __builtin_amdgcn_sched_barrier(0);
        __builtin_amdgcn_s_barrier();                   // all waves' DMA for tile t visible
        __builtin_amdgcn_sched_barrier(0);
        __builtin_amdgcn_s_setprio(1);
        const u16* Ab = &lds[p * 24576];
        const u16* Bb = &lds[p * 24576 + 16384];
#pragma unroll
        for (int kt = 0; kt < 4; ++kt) {
            const int cs = (((kt * 2 + hf) ^ (l32 & 7)) * 8);   // swizzled slot read
            short8 af[2], bfr[2];
#pragma unroll
            for (int mb = 0; mb < 2; ++mb)
                af[mb] = *(const short8*)&Ab[(wm * 64 + mb * 32 + l32) * 64 + cs];
#pragma unroll
            for (int nb = 0; nb < 2; ++nb)
                bfr[nb] = *(const short8*)&Bb[(wn * 64 + nb * 32 + l32) * 64 + cs];
#pragma unroll
            for (int mb = 0; mb < 2; ++mb)
#pragma unroll
                for (int nb = 0; nb < 2; ++nb)
                    acc[mb][nb] = __builtin_amdgcn_mfma_f32_32x32x16_bf16(af[mb], bfr[nb], acc[mb][nb], 0, 0, 0);
        }
        __builtin_amdgcn_s_setprio(0);
        __builtin_amdgcn_sched_barrier(0);
        __builtin_amdgcn_s_barrier();                   // all waves done reading buf p
        __builtin_amdgcn_sched_barrier(0);
        if (t + 2 < NTt) STAGE(p, (t + 2) * 64);        // overwrite freed buf p
    }

    // EPI==4: per-block output select (block is entirely Q-side or K-side)
    u16* dst4 = nullptr;
    float sc4 = 1.0f;
    if (EPI == 4) {
        const bool isK = (n0 >= 1024);
        dst4 = isK ? (u16*)Cout2 : (u16*)Cout;
        sc4 = isK ? 1.0f : oscale;
    }

#pragma unroll
    for (int mb = 0; mb < 2; ++mb)
#pragma unroll
        for (int nb = 0; nb < 2; ++nb) {
            const int col = n0 + wn * 64 + nb * 32 + l32;
#pragma unroll
            for (int r = 0; r < 16; ++r) {
                const int row = m0 + wm * 64 + mb * 32 + (r & 3) + 8 * (r >> 2) + 4 * hf;
                float v = acc[mb][nb][r];
                const size_t idx = (size_t)row * N + col;
                if (EPI == 0) {
                    ((u16*)Cout)[idx] = f2bf(v * oscale);
                } else if (EPI == 1) {
                    ((float*)Cout)[idx] = v + ((const float*)resid)[idx];
                } else if (EPI == 2) {
                    v += bias[col];
                    ((u16*)Cout)[idx] = f2bf(fmaxf(v, 0.f));
                } else if (EPI == 3) {
                    v += bias[col] + bf2f(((const u16*)resid)[idx]);
                    ((float*)Cout)[idx] = v;
                } else {
                    dst4[(size_t)row * 1024 + (col & 1023)] = f2bf(v * sc4);
                }
            }
        }
}

// ---------------------------------------------------------------------------
// Attention pass 1 (32x32 MFMA) + fused V-scale, TWO t-tiles per block.
// l_t = sum_s exp2(score'); then Vt[h*64+d][b*SS+t] *= 0.125/l_t in the tail.
// K B-frags for both t-tiles in regs (kfA: t0.., kfB: t0+128..); every Q
// A-fragment LDS read feeds 2 MFMAs (cross-wave redundancy amortized — the
// same lever that won pv_fused R6).  s-halves processed sequentially so only
// scA+scB live.  Q staged in double-buffered XOR-swizzled LDS, ONE barrier
// per iter; single-v_exp (Q pre-scaled by log2e).
// 1-D grid 512, XCD swizzle groups all 8 t-groups of a (b,h) on one XCD.
// ---------------------------------------------------------------------------
__global__ __launch_bounds__(256) void stats32(const u16* __restrict__ Qg,
                                               const u16* __restrict__ Kg,
                                               u16* __restrict__ Vtg) {
    __shared__ u16 Qs[2][64 * 64];   // [dbuf][s][d], swizzled 128B rows
    __shared__ float lbuf[256];
    const int bid = blockIdx.x;                    // nwg = 512 (div by 8)
    const int wgid = (bid & 7) * 64 + (bid >> 3);  // 64 consecutive per XCD
    const int t0 = (wgid & 7) * 256;
    const int bh = wgid >> 3;
    const int b = bh >> 4, h = bh & 15;
    const int tid = threadIdx.x;
    const int w = tid >> 6, l = tid & 63;
    const int l32 = l & 31, hf = l >> 5;
    const u16* Qp = Qg + (size_t)b * SS * 1024 + h * 64;
    const u16* Kp = Kg + (size_t)b * SS * 1024 + h * 64;
    const int sr = tid >> 3, dg = (tid & 7) * 8;   // staging row / u16 chunk

    // K B-frags, two t-tiles: A cols t0 + w*32 + l32, B cols t0+128 + w*32 + l32
    short8 kfA[4], kfB[4];
#pragma unroll
    for (int ks = 0; ks < 4; ++ks) {
        kfA[ks] = *(const short8*)(Kp + (size_t)(t0 + w * 32 + l32) * 1024 + ks * 16 + hf * 8);
        kfB[ks] = *(const short8*)(Kp + (size_t)(t0 + 128 + w * 32 + l32) * 1024 + ks * 16 + hf * 8);
    }

    // prologue: tile 0 -> buf0, tile 1 -> regs
    short8 pq0 = *(const short8*)(Qp + (size_t)sr * 1024 + dg);
    short8 pq1 = *(const short8*)(Qp + (size_t)(sr + 32) * 1024 + dg);
    *(short8*)((char*)Qs[0] + sw(sr, dg * 2)) = pq0;
    *(short8*)((char*)Qs[0] + sw(sr + 32, dg * 2)) = pq1;
    pq0 = *(const short8*)(Qp + (size_t)(64 + sr) * 1024 + dg);
    pq1 = *(const short8*)(Qp + (size_t)(64 + sr + 32) * 1024 + dg);
    __syncthreads();

    float lsA = 0.f, lsB = 0.f;
    for (int st = 0; st < 32; ++st) {
        const int p = st & 1;
        if (st + 1 < 32) {   // stage tile st+1 (regs loaded last iter / prologue)
            *(short8*)((char*)Qs[p ^ 1] + sw(sr, dg * 2)) = pq0;
            *(short8*)((char*)Qs[p ^ 1] + sw(sr + 32, dg * 2)) = pq1;
        }
        if (st + 2 < 32) {   // issue tile st+2 global loads (hidden under MFMA)
            const int s1 = (st + 2) * 64;
            pq0 = *(const short8*)(Qp + (size_t)(s1 + sr) * 1024 + dg);
            pq1 = *(const short8*)(Qp + (size_t)(s1 + sr + 32) * 1024 + dg);
        }
        // s-halves sequential: one Q-frag read feeds both t-tiles' MFMAs
#pragma unroll
        for (int half = 0; half < 2; ++half) {
            f32x16 scA = {}, scB = {};
            __builtin_amdgcn_s_setprio(1);
#pragma unroll
            for (int ks = 0; ks < 4; ++ks) {
                short8 a0 = *(const short8*)((char*)Qs[p] + sw(half * 32 + l32, ks * 32 + hf * 16));
                scA = __builtin_amdgcn_mfma_f32_32x32x16_bf16(a0, kfA[ks], scA, 0, 0, 0);
                scB = __builtin_amdgcn_mfma_f32_32x32x16_bf16(a0, kfB[ks], scB, 0, 0, 0);
            }
            __builtin_amdgcn_s_setprio(0);
#pragma unroll
            for (int r = 0; r < 16; ++r) { lsA += ex2(scA[r]); lsB += ex2(scB[r]); }
        }
        __syncthreads();   // release buf p, publish buf p^1
    }
    lsA += __shfl_xor(lsA, 32);            // combine hf halves (same t)
    lsB += __shfl_xor(lsB, 32);
    if (hf == 0) {
        lbuf[w * 32 + l32] = 0.125f / lsA;
        lbuf[128 + w * 32 + l32] = 0.125f / lsB;
    }
    __syncthreads();

    // fused vscale: 64 rows (d) x 256 cols (t); thread = (d = tid>>2, 64 cols)
    const int d = tid >> 2, cb = (tid & 3) * 64;
    u16* vp = Vtg + (size_t)(h * 64 + d) * 8192 + b * SS + t0 + cb;
#pragma unroll
    for (int j = 0; j < 8; ++j) {
        short8 v = *(short8*)(vp + j * 8);
        short8 o;
#pragma unroll
        for (int i = 0; i < 8; ++i)
            o[i] = (short)f2bf(bf2f((u16)v[i]) * lbuf[cb + j * 8 + i]);
        *(short8*)(vp + j * 8) = o;
    }
}

// ---------------------------------------------------------------------------
// Attention pass 2 (fused), 32x32x16 MFMA with in-register P.
// Each wave owns TWO s-blocks (A: s0+w*32, B: s0+128+w*32); every K/V LDS
// fragment read feeds 2 MFMAs -> LDS reads per MFMA halved (cross-wave
// redundancy amortized in-register).  Iteration processes t-halves (th=0:
// t 0..31, th=1: t 32..63) sequentially so only one sc pair is live.
// Double-buffered K/V LDS tiles, ONE barrier per iter.  P = bf16(exp2(S))
// via cvt_pk + permlane32_swap (R3-proven copy + pl32swap2 pattern).
// 1-D grid 512 with XCD swizzle (8 bh per XCD; K/V L2-resident).
// ---------------------------------------------------------------------------
__global__ __launch_bounds__(256) void pv_fused(const u16* __restrict__ Qg,
                                                const u16* __restrict__ Kg,
                                                const u16* __restrict__ Vtg,
                                                u16* __restrict__ vecbf) {
    __shared__ u16 Ks[2][64 * 64];   // [dbuf][t][d], swizzled 128B rows
    __shared__ u16 Vs[2][64 * 64];   // [dbuf][d][t], swizzled 128B rows
    const int bid = blockIdx.x;                    // nwg = 512
    const int wgid = (bid & 7) * 64 + (bid >> 3);  // 64 consecutive per XCD
    const int s0 = (wgid & 7) * 256;
    const int bh = wgid >> 3;
    const int b = bh >> 4, h = bh & 15;
    const int tid = threadIdx.x;
    const int w = tid >> 6, l = tid & 63;
    const int l32 = l & 31, hf = l >> 5;
    const u16* Qp = Qg + (size_t)b * SS * 1024 + h * 64;
    const u16* Kp = Kg + (size_t)b * SS * 1024 + h * 64;
    const u16* Vp = Vtg + (size_t)h * 64 * 8192 + (size_t)b * SS;
    const int sr = tid >> 3, dg = (tid & 7) * 8;   // staging row / u16 chunk

    // Q B-frags (loop-invariant), two s-blocks per wave:
    //   A: col s = s0 + w*32 + l32;  B: col s = s0 + 128 + w*32 + l32
    short8 qfA[4], qfB[4];
#pragma unroll
    for (int ks = 0; ks < 4; ++ks) {
        qfA[ks] = *(const short8*)(Qp + (size_t)(s0 + w * 32 + l32) * 1024 + ks * 16 + hf * 8);
        qfB[ks] = *(const short8*)(Qp + (size_t)(s0 + 128 + w * 32 + l32) * 1024 + ks * 16 + hf * 8);
    }

    // prologue: tile 0 -> buf0, tile 1 -> regs
    short8 pk0 = *(const short8*)(Kp + (size_t)sr * 1024 + dg);
    short8 pk1 = *(const short8*)(Kp + (size_t)(sr + 32) * 1024 + dg);
    short8 pv0 = *(const short8*)(Vp + (size_t)sr * 8192 + dg);
    short8 pv1 = *(const short8*)(Vp + (size_t)(sr + 32) * 8192 + dg);
    *(short8*)((char*)Ks[0] + sw(sr, dg * 2)) = pk0;
    *(short8*)((char*)Ks[0] + sw(sr + 32, dg * 2)) = pk1;
    *(short8*)((char*)Vs[0] + sw(sr, dg * 2)) = pv0;
    *(short8*)((char*)Vs[0] + sw(sr + 32, dg * 2)) = pv1;
    pk0 = *(const short8*)(Kp + (size_t)(64 + sr) * 1024 + dg);
    pk1 = *(const short8*)(Kp + (size_t)(64 + sr + 32) * 1024 + dg);
    pv0 = *(const short8*)(Vp + (size_t)sr * 8192 + 64 + dg);
    pv1 = *(const short8*)(Vp + (size_t)(sr + 32) * 8192 + 64 + dg);
    __syncthreads();

    f32x16 accA[2] = {}, accB[2] = {};   // O[s][d] for the two s-blocks
    for (int tt = 0; tt < 32; ++tt) {
        const int p = tt & 1;
        if (tt + 1 < 32) {   // stage tile tt+1
            *(short8*)((char*)Ks[p ^ 1] + sw(sr, dg * 2)) = pk0;
            *(short8*)((char*)Ks[p ^ 1] + sw(sr + 32, dg * 2)) = pk1;
            *(short8*)((char*)Vs[p ^ 1] + sw(sr, dg * 2)) = pv0;
            *(short8*)((char*)Vs[p ^ 1] + sw(sr + 32, dg * 2)) = pv1;
        }
        if (tt + 2 < 32) {   // issue tile tt+2 loads
            const int t1 = (tt + 2) * 64;
            pk0 = *(const short8*)(Kp + (size_t)(t1 + sr) * 1024 + dg);
            pk1 = *(const short8*)(Kp + (size_t)(t1 + sr + 32) * 1024 + dg);
            pv0 = *(const short8*)(Vp + (size_t)sr * 8192 + t1 + dg);
            pv1 = *(const short8*)(Vp + (size_t)(sr + 32) * 8192 + t1 + dg);
        }
        // t-halves: th covers tile rows t in [th*32, th*32+32)
#pragma unroll
        for (int th = 0; th < 2; ++th) {
            // S^T[t][s]: A-operand = K rows (th*32 + l32), one read feeds both
            // s-blocks.  C: col=s=l32, row t = th*32 + (reg&3)+8*(reg>>2)+4*hf
            f32x16 scA = {}, scB = {};
            __builtin_amdgcn_s_setprio(1);
#pragma unroll
            for (int ks = 0; ks < 4; ++ks) {
                short8 a0 = *(const short8*)((char*)Ks[p] + sw(th * 32 + l32, ks * 32 + hf * 16));
                scA = __builtin_amdgcn_mfma_f32_32x32x16_bf16(a0, qfA[ks], scA, 0, 0, 0);
                scB = __builtin_amdgcn_mfma_f32_32x32x16_bf16(a0, qfB[ks], scB, 0, 0, 0);
            }
            __builtin_amdgcn_s_setprio(0);
            // P = exp2(S) -> packed bf16 pairs (t, t+1) per u32
            unsigned cpA[8], cpB[8];
#pragma unroll
            for (int p2 = 0; p2 < 8; ++p2) {
                cpA[p2] = cvtpk(ex2(scA[2 * p2]), ex2(scA[2 * p2 + 1]));
                cpB[p2] = cvtpk(ex2(scB[2 * p2]), ex2(scB[2 * p2 + 1]));
            }
            // A-frags for PV: ks2 = th*2 + q covers t = 16*ks2 + 8*hf + j
            short8 paA[2], paB[2];
#pragma unroll
            for (int q = 0; q < 2; ++q) {
                const int c = q * 4;
                unsigned a0w = cpA[c + 0], a2w = cpA[c + 2];
                unsigned a1w = cpA[c + 1], a3w = cpA[c + 3];
                pl32swap2(a0w, a2w, a1w, a3w);
                u32x4 tA; tA.x = a0w; tA.y = a1w; tA.z = a2w; tA.w = a3w;
                paA[q] = __builtin_bit_cast(short8, tA);
                unsigned b0w = cpB[c + 0], b2w = cpB[c + 2];
                unsigned b1w = cpB[c + 1], b3w = cpB[c + 3];
                pl32swap2(b0w, b2w, b1w, b3w);
                u32x4 tB; tB.x = b0w; tB.y = b1w; tB.z = b2w; tB.w = b3w;
                paB[q] = __builtin_bit_cast(short8, tB);
            }
            // O += P @ Vtilde: each V frag read feeds both s-blocks
            __builtin_amdgcn_s_setprio(1);
#pragma unroll
            for (int q = 0; q < 2; ++q) {
                const int ks2 = th * 2 + q;
#pragma unroll
                for (int nf = 0; nf < 2; ++nf) {
                    short8 bfr = *(const short8*)((char*)Vs[p] + sw(nf * 32 + l32, ks2 * 32 + hf * 16));
                    accA[nf] = __builtin_amdgcn_mfma_f32_32x32x16_bf16(paA[q], bfr, accA[nf], 0, 0, 0);
                    accB[nf] = __builtin_amdgcn_mfma_f32_32x32x16_bf16(paB[q], bfr, accB[nf], 0, 0, 0);
                }
            }
            __builtin_amdgcn_s_setprio(0);
        }
        __syncthreads();   // release buf p, publish buf p^1
    }
#pragma unroll
    for (int nf = 0; nf < 2; ++nf) {
        const int col = h * 64 + nf * 32 + l32;
#pragma unroll
        for (int r = 0; r < 16; ++r) {
            const int ro = (r & 3) + 8 * (r >> 2) + 4 * hf;
            const int srowA = s0 + w * 32 + ro;
            vecbf[(size_t)(b * SS + srowA) * 1024 + col] = f2bf(accA[nf][r]);
            const int srowB = s0 + 128 + w * 32 + ro;
            vecbf[(size_t)(b * SS + srowB) * 1024 + col] = f2bf(accB[nf][r]);
        }
    }
}

// ---------------------------------------------------------------------------
// LayerNorm over last dim (E=1024), fp32 in -> bf16 out
// ---------------------------------------------------------------------------
__global__ __launch_bounds__(256) void ln_bf_kernel(const float* __restrict__ buf,
                                                    const float* __restrict__ g,
                                                    const float* __restrict__ be,
                                                    u16* __restrict__ outbf) {
    const int row = blockIdx.x;
    const int tid = threadIdx.x;
    const float* p = buf + (size_t)row * EE;
    float4 x = reinterpret_cast<const float4*>(p)[tid];
    float s = x.x + x.y + x.z + x.w;
    __shared__ float red[4];
#pragma unroll
    for (int o = 32; o > 0; o >>= 1) s += __shfl_down(s, o);
    const int wid = tid >> 6, lane = tid & 63;
    if (lane == 0) red[wid] = s;
    __syncthreads();
    const float mu = (red[0] + red[1] + red[2] + red[3]) * (1.0f / EE);
    __syncthreads();
    const float dx = x.x - mu, dy = x.y - mu, dz = x.z - mu, dw = x.w - mu;
    float v = dx * dx + dy * dy + dz * dz + dw * dw;
#pragma unroll
    for (int o = 32; o > 0; o >>= 1) v += __shfl_down(v, o);
    if (lane == 0) red[wid] = v;
    __syncthreads();
    const float var = (red[0] + red[1] + red[2] + red[3]) * (1.0f / EE);
    const float rs = rsqrtf(var + 1e-5f);
    float4 gv = reinterpret_cast<const float4*>(g)[tid];
    float4 bv = reinterpret_cast<const float4*>(be)[tid];
    short4v o;
    o.x = (short)f2bf(dx * rs * gv.x + bv.x);
    o.y = (short)f2bf(dy * rs * gv.y + bv.y);
    o.z = (short)f2bf(dz * rs * gv.z + bv.z);
    o.w = (short)f2bf(dw * rs * gv.w + bv.w);
    reinterpret_cast<short4v*>(outbf + (size_t)row * EE)[tid] = o;
}

// In-place fp32 LayerNorm (final output)
__global__ __launch_bounds__(256) void ln_kernel(float* __restrict__ buf,
                                                 const float* __restrict__ g,
                                                 const float* __restrict__ be) {
    const int row = blockIdx.x;
    const int tid = threadIdx.x;
    float* p = buf + (size_t)row * EE;
    float4 x = reinterpret_cast<float4*>(p)[tid];
    float s = x.x + x.y + x.z + x.w;
    __shared__ float red[4];
#pragma unroll
    for (int o = 32; o > 0; o >>= 1) s += __shfl_down(s, o);
    const int wid = tid >> 6, lane = tid & 63;
    if (lane == 0) red[wid] = s;
    __syncthreads();
    const float mu = (red[0] + red[1] + red[2] + red[3]) * (1.0f / EE);
    __syncthreads();
    const float dx = x.x - mu, dy = x.y - mu, dz = x.z - mu, dw = x.w - mu;
    float v = dx * dx + dy * dy + dz * dz + dw * dw;
#pragma unroll
    for (int o = 32; o > 0; o >>= 1) v += __shfl_down(v, o);
    if (lane == 0) red[wid] = v;
    __syncthreads();
    const float var = (red[0] + red[1] + red[2] + red[3]) * (1.0f / EE);
    const float rs = rsqrtf(var + 1e-5f);
    float4 gv = reinterpret_cast<const float4*>(g)[tid];
    float4 bv = reinterpret_cast<const float4*>(be)[tid];
    float4 y;
    y.x = dx * rs * gv.x + bv.x;
    y.y = dy * rs * gv.y + bv.y;
    y.z = dz * rs * gv.z + bv.z;
    y.w = dw * rs * gv.w + bv.w;
    reinterpret_cast<float4*>(p)[tid] = y;
}

// ---------------------------------------------------------------------------
extern "C" void kernel_launch(void* const* d_in, const int* in_sizes, int n_in,
                              void* d_out, int out_size, void* d_ws, size_t ws_size,
                              hipStream_t stream) {
    const float* X     = (const float*)d_in[0];
    const float* WQ    = (const float*)d_in[1];
    const float* WK    = (const float*)d_in[2];
    const float* WV    = (const float*)d_in[3];
    const float* WO    = (const float*)d_in[4];
    const float* gamma = (const float*)d_in[5];
    const float* beta  = (const float*)d_in[6];
    const float* W1    = (const float*)d_in[7];
    const float* b1    = (const float*)d_in[8];
    const float* W2    = (const float*)d_in[9];
    const float* b2    = (const float*)d_in[10];
    float* out = (float*)d_out;

    char* ws = (char*)d_ws;
    const size_t MB = 1024 * 1024;
    u16* WQT   = (u16*)(ws + 0);          // 2 MB [H][D][E]   (WQT|WKT contiguous
    u16* WKT   = (u16*)(ws + 2 * MB);     //  -> fused [2048][1024] B for QK proj)
    u16* WVT   = (u16*)(ws + 4 * MB);
    u16* WOT   = (u16*)(ws + 6 * MB);     // 2 MB [E][H*D]
    u16* W1T   = (u16*)(ws + 8 * MB);     // 8 MB [F][E]
    u16* W2T   = (u16*)(ws + 16 * MB);    // 8 MB [E][F]
    u16* Qbf   = (u16*)(ws + 25 * MB);    // 16 MB [B*S][H*D] (pre-scaled by log2e)
    u16* Kbf   = (u16*)(ws + 41 * MB);    // 16 MB
    u16* Vt    = (u16*)(ws + 57 * MB);    // 16 MB [H*D][B*S]
    u16* vecbf = (u16*)(ws + 73 * MB);    // 16 MB att_vec bf16
    u16* hid   = (u16*)(ws + 25 * MB);    // 64 MB FFN hidden, overlays Q/K/Vt/vec
    u16* Xbf   = (u16*)(ws + 89 * MB);    // 16 MB
    float* vatt  = (float*)(ws + 105 * MB); // 32 MB fp32 (pre-LN1)
    u16*   ln1bf = (u16*)(ws + 137 * MB);   // 16 MB LN1 out

    const int NT = BB * SS;   // 8192 tokens

    // --- one-time converts / weight transposes (bf16, k-innermost) ---
    cvt_bf<<<8192, 256, 0, stream>>>(X, Xbf, NT * EE / 4);
    transp_bf<<<dim3(16, 1, 16), 256, 0, stream>>>(WQ, WQT, EE, DD);
    transp_bf<<<dim3(16, 1, 16), 256, 0, stream>>>(WK, WKT, EE, DD);
    transp_bf<<<dim3(16, 1, 16), 256, 0, stream>>>(WV, WVT, EE, DD);
    transp_bf<<<dim3(16, 16, 1), 256, 0, stream>>>(WO, WOT, HH * DD, EE);
    transp_bf<<<dim3(16, 64, 1), 256, 0, stream>>>(W1, W1T, EE, FF);
    transp_bf<<<dim3(64, 16, 1), 256, 0, stream>>>(W2, W2T, FF, EE);

    // --- projections: Q+K fused (B = [WQT;WKT] contiguous, 512 blocks);
    //     Q scaled by log2e so attention exp == single v_exp_f32 ---
    gemm256<4><<<512, 512, 0, stream>>>(Xbf, WQT, 1024, 2048, 16, Qbf, nullptr, nullptr, 1.44269504089f, Kbf);
    gemm256<0><<<256, 512, 0, stream>>>(WVT, Xbf, 1024, 8192, 64, Vt, nullptr, nullptr, 1.0f, nullptr);

    // --- attention (column softmax then /8), fused path ---
    stats32<<<512, 256, 0, stream>>>(Qbf, Kbf, Vt);           // l stats + V scale
    pv_fused<<<512, 256, 0, stream>>>(Qbf, Kbf, Vt, vecbf);

    // --- WO + residual X -> vatt (fp32), LN1 -> ln1bf ---
    gemm256<1><<<256, 512, 0, stream>>>(vecbf, WOT, 1024, 1024, 8, vatt, nullptr, X, 1.0f, nullptr);
    ln_bf_kernel<<<NT, 256, 0, stream>>>(vatt, gamma, beta, ln1bf);

    // --- FFN ---
    gemm256<2><<<1024, 512, 0, stream>>>(ln1bf, W1T, 1024, FF, 32, hid, b1, nullptr, 1.0f, nullptr);
    gemm256<3><<<256, 512, 0, stream>>>(hid, W2T, FF, 1024, 8, out, b2, ln1bf, 1.0f, nullptr);

    // --- final LN in place on d_out ---
    ln_kernel<<<NT, 256, 0, stream>>>(out, gamma, beta);
}